// Round 1
// baseline (1972.830 us; speedup 1.0000x reference)
//
#include <hip/hip_runtime.h>
#include <cstddef>

#define BATCH_N 32768
#define UNITS_N 256
#define IN_DIM 784
#define OUT_DIM 10
#define NLAYERS 8

// ============================================================================
// Big GEMM: Out[u,b] = EPI( sum_k AT[k*256+u] * In[k*BATCH_N+b] )
// A is always accessed "k-major" (AT[k][u]) => coalesced. For row-major
// operands we pass a transposed copy (B^T) or exploit symmetry (Minv).
// BM=BN=128, BK=16, 256 threads, 8x8 microtile split as (4+4)x(4+4) so LDS
// reads are contiguous float4 spans (2-way bank aliasing = free on gfx950).
// EPI 0: out = acc
// EPI 1: out = acc + P2[idx] + tanh(P1[idx]) + rowv[u]*rowscale    (t-GEMM)
// EPI 2: out = P1[idx] + rowv[u]*rowscale - acc                    (z0-GEMM)
// ============================================================================
template<int EPI>
__launch_bounds__(256)
__global__ void gemm_layer(const float* __restrict__ AT, const float* __restrict__ In,
                           float* __restrict__ Out,
                           const float* __restrict__ P1, const float* __restrict__ P2,
                           const float* __restrict__ rowv, float rowscale)
{
    __shared__ float As[16][128];
    __shared__ float Bs[16][128];
    const int t  = threadIdx.x;
    const int tx = t & 15, ty = t >> 4;
    const int u0 = blockIdx.y * 128;
    const int c0 = blockIdx.x * 128;
    const int lk = t >> 4;          // 0..15
    const int lu = (t & 15) << 3;   // 0,8,...,120

    float acc[2][2][4][4];
#pragma unroll
    for (int h = 0; h < 2; ++h)
#pragma unroll
        for (int w = 0; w < 2; ++w)
#pragma unroll
            for (int m = 0; m < 4; ++m)
#pragma unroll
                for (int n = 0; n < 4; ++n) acc[h][w][m][n] = 0.f;

    for (int k0 = 0; k0 < 256; k0 += 16) {
        __syncthreads();
        const float* pa = AT + (size_t)(k0 + lk) * 256 + u0 + lu;
        *(float4*)&As[lk][lu]     = *(const float4*)(pa);
        *(float4*)&As[lk][lu + 4] = *(const float4*)(pa + 4);
        const float* pb = In + (size_t)(k0 + lk) * BATCH_N + c0 + lu;
        *(float4*)&Bs[lk][lu]     = *(const float4*)(pb);
        *(float4*)&Bs[lk][lu + 4] = *(const float4*)(pb + 4);
        __syncthreads();
#pragma unroll
        for (int kk = 0; kk < 16; ++kk) {
            float af[8], bf[8];
            *(float4*)&af[0] = *(const float4*)&As[kk][ty * 4];
            *(float4*)&af[4] = *(const float4*)&As[kk][64 + ty * 4];
            *(float4*)&bf[0] = *(const float4*)&Bs[kk][tx * 4];
            *(float4*)&bf[4] = *(const float4*)&Bs[kk][64 + tx * 4];
#pragma unroll
            for (int h = 0; h < 2; ++h)
#pragma unroll
                for (int m = 0; m < 4; ++m)
#pragma unroll
                    for (int w = 0; w < 2; ++w)
#pragma unroll
                        for (int n = 0; n < 4; ++n)
                            acc[h][w][m][n] += af[h * 4 + m] * bf[w * 4 + n];
        }
    }

#pragma unroll
    for (int h = 0; h < 2; ++h) {
#pragma unroll
        for (int m = 0; m < 4; ++m) {
            const int u = u0 + h * 64 + ty * 4 + m;
            float rv = 0.f;
            if (EPI == 1 || EPI == 2) rv = rowv[u] * rowscale;
#pragma unroll
            for (int w = 0; w < 2; ++w) {
                const size_t idx = (size_t)u * BATCH_N + c0 + w * 64 + tx * 4;
                float4 r;
                float* rf = &r.x;
                if (EPI == 0) {
#pragma unroll
                    for (int n = 0; n < 4; ++n) rf[n] = acc[h][w][m][n];
                } else if (EPI == 1) {
                    float4 p1 = *(const float4*)&P1[idx];
                    float4 p2 = *(const float4*)&P2[idx];
                    const float* p1f = &p1.x; const float* p2f = &p2.x;
#pragma unroll
                    for (int n = 0; n < 4; ++n)
                        rf[n] = acc[h][w][m][n] + p2f[n] + tanhf(p1f[n]) + rv;
                } else {
                    float4 p1 = *(const float4*)&P1[idx];
                    const float* p1f = &p1.x;
#pragma unroll
                    for (int n = 0; n < 4; ++n)
                        rf[n] = p1f[n] + rv - acc[h][w][m][n];
                }
                *(float4*)&Out[idx] = r;
            }
        }
    }
}

// ============================================================================
// Input GEMM: V0[u,b] = sum_k x[b,k]*W_in[k,u] + b_in[u];  V1 = tanh(V0)
// x tile is transposed into LDS (x is b-major, we need k-major).
// ============================================================================
__launch_bounds__(256)
__global__ void gemm_input(const float* __restrict__ x, const float* __restrict__ Wi,
                           const float* __restrict__ bi,
                           float* __restrict__ V0, float* __restrict__ V1)
{
    __shared__ float As[16][128];
    __shared__ float Bs[16][128];
    const int t  = threadIdx.x;
    const int tx = t & 15, ty = t >> 4;
    const int u0 = blockIdx.y * 128;
    const int c0 = blockIdx.x * 128;
    const int lk = t >> 4;
    const int lu = (t & 15) << 3;
    const int bcol = t >> 1;        // 0..127
    const int kh   = (t & 1) * 8;   // 0 or 8

    float acc[2][2][4][4];
#pragma unroll
    for (int h = 0; h < 2; ++h)
#pragma unroll
        for (int w = 0; w < 2; ++w)
#pragma unroll
            for (int m = 0; m < 4; ++m)
#pragma unroll
                for (int n = 0; n < 4; ++n) acc[h][w][m][n] = 0.f;

    for (int k0 = 0; k0 < IN_DIM; k0 += 16) {
        __syncthreads();
        const float* pa = Wi + (size_t)(k0 + lk) * 256 + u0 + lu;
        *(float4*)&As[lk][lu]     = *(const float4*)(pa);
        *(float4*)&As[lk][lu + 4] = *(const float4*)(pa + 4);
        const float* px = x + (size_t)(c0 + bcol) * IN_DIM + k0 + kh;
        float4 x0 = *(const float4*)px;
        float4 x1 = *(const float4*)(px + 4);
        const float* xf0 = &x0.x; const float* xf1 = &x1.x;
#pragma unroll
        for (int r = 0; r < 4; ++r) Bs[kh + r][bcol]     = xf0[r];
#pragma unroll
        for (int r = 0; r < 4; ++r) Bs[kh + 4 + r][bcol] = xf1[r];
        __syncthreads();
#pragma unroll
        for (int kk = 0; kk < 16; ++kk) {
            float af[8], bf[8];
            *(float4*)&af[0] = *(const float4*)&As[kk][ty * 4];
            *(float4*)&af[4] = *(const float4*)&As[kk][64 + ty * 4];
            *(float4*)&bf[0] = *(const float4*)&Bs[kk][tx * 4];
            *(float4*)&bf[4] = *(const float4*)&Bs[kk][64 + tx * 4];
#pragma unroll
            for (int h = 0; h < 2; ++h)
#pragma unroll
                for (int m = 0; m < 4; ++m)
#pragma unroll
                    for (int w = 0; w < 2; ++w)
#pragma unroll
                        for (int n = 0; n < 4; ++n)
                            acc[h][w][m][n] += af[h * 4 + m] * bf[w * 4 + n];
        }
    }

#pragma unroll
    for (int h = 0; h < 2; ++h) {
#pragma unroll
        for (int m = 0; m < 4; ++m) {
            const int u = u0 + h * 64 + ty * 4 + m;
            const float bu = bi[u];
#pragma unroll
            for (int w = 0; w < 2; ++w) {
                const size_t idx = (size_t)u * BATCH_N + c0 + w * 64 + tx * 4;
                float4 r0v, r1v;
                float* r0f = &r0v.x; float* r1f = &r1v.x;
#pragma unroll
                for (int n = 0; n < 4; ++n) {
                    float v = acc[h][w][m][n] + bu;
                    r0f[n] = v;
                    r1f[n] = tanhf(v);
                }
                *(float4*)&V0[idx] = r0v;
                *(float4*)&V1[idx] = r1v;
            }
        }
    }
}

// ============================================================================
// Batched 256x256x256 GEMM over 8 matrices: D_i[u,v] = EPI(sum_k A_i[k*256+u]*B_i[k*256+v])
// (A accessed k-major; all our operands are symmetric or naturally k-major.)
// EPI 0: D = acc;  EPI 1: D = acc + 2I;  EPI 2: D = 2*E - acc
// ============================================================================
template<int EPI>
__launch_bounds__(256)
__global__ void gemm256b(float* __restrict__ D, const float* __restrict__ A,
                         const float* __restrict__ Bm, const float* __restrict__ E)
{
    __shared__ float As[16][64];
    __shared__ float Bs[16][64];
    const int i = blockIdx.z;
    const size_t off = (size_t)i * 65536;
    const float* Ai = A + off;
    const float* Bi = Bm + off;
    const int t  = threadIdx.x;
    const int tx = t & 15, ty = t >> 4;
    const int u0 = blockIdx.y * 64, v0 = blockIdx.x * 64;
    const int lk = t >> 4, lv = (t & 15) << 2;

    float acc[4][4];
#pragma unroll
    for (int m = 0; m < 4; ++m)
#pragma unroll
        for (int n = 0; n < 4; ++n) acc[m][n] = 0.f;

    for (int k0 = 0; k0 < 256; k0 += 16) {
        __syncthreads();
        *(float4*)&As[lk][lv] = *(const float4*)(Ai + (size_t)(k0 + lk) * 256 + u0 + lv);
        *(float4*)&Bs[lk][lv] = *(const float4*)(Bi + (size_t)(k0 + lk) * 256 + v0 + lv);
        __syncthreads();
#pragma unroll
        for (int kk = 0; kk < 16; ++kk) {
            float af[4], bf[4];
            *(float4*)&af[0] = *(const float4*)&As[kk][ty * 4];
            *(float4*)&bf[0] = *(const float4*)&Bs[kk][tx * 4];
#pragma unroll
            for (int m = 0; m < 4; ++m)
#pragma unroll
                for (int n = 0; n < 4; ++n) acc[m][n] += af[m] * bf[n];
        }
    }

#pragma unroll
    for (int m = 0; m < 4; ++m) {
        const int u = u0 + ty * 4 + m;
        const size_t idx = off + (size_t)u * 256 + v0 + tx * 4;
        float4 r; float* rf = &r.x;
        if (EPI == 0) {
#pragma unroll
            for (int n = 0; n < 4; ++n) rf[n] = acc[m][n];
        } else if (EPI == 1) {
#pragma unroll
            for (int n = 0; n < 4; ++n)
                rf[n] = acc[m][n] + ((u == v0 + tx * 4 + n) ? 2.f : 0.f);
        } else {
            float4 e = *(const float4*)&E[idx];
            const float* ef = &e.x;
#pragma unroll
            for (int n = 0; n < 4; ++n) rf[n] = 2.f * ef[n] - acc[m][n];
        }
        *(float4*)&D[idx] = r;
    }
}

// Bt_i[k*256+u] = B_i[u*256+k]
__launch_bounds__(256)
__global__ void transpose256(const float* __restrict__ src, float* __restrict__ dst)
{
    __shared__ float tl[32][33];
    const int i = blockIdx.z;
    const float* S = src + (size_t)i * 65536;
    float* Dst = dst + (size_t)i * 65536;
    const int u0 = blockIdx.y * 32, k0 = blockIdx.x * 32;
    const int tx = threadIdx.x, ty = threadIdx.y; // 32 x 8
#pragma unroll
    for (int r = 0; r < 32; r += 8) tl[ty + r][tx] = S[(size_t)(u0 + ty + r) * 256 + k0 + tx];
    __syncthreads();
#pragma unroll
    for (int r = 0; r < 32; r += 8) Dst[(size_t)(k0 + ty + r) * 256 + u0 + tx] = tl[tx][ty + r];
}

// bq_i[u] = 0.1 * sum_k B_i[k,u] * q_i[k]
__launch_bounds__(256)
__global__ void bq_kernel(const float* __restrict__ B0, const float* __restrict__ q,
                          float* __restrict__ bq)
{
    __shared__ float qs[256];
    const int i = blockIdx.x;
    const int u = threadIdx.x;
    qs[u] = q[i * 256 + u];
    __syncthreads();
    float s = 0.f;
    for (int k = 0; k < 256; ++k) s += B0[(size_t)i * 65536 + (size_t)k * 256 + u] * qs[k];
    bq[i * 256 + u] = 0.1f * s;
}

// alpha_i = ||C_i||_inf  (= max column abs-sum; C symmetric => coalesced column sums)
__launch_bounds__(256)
__global__ void alpha_kernel(const float* __restrict__ C, float* __restrict__ alpha)
{
    __shared__ float red[256];
    const int i = blockIdx.x;
    const int u = threadIdx.x;
    float s = 0.f;
    for (int v = 0; v < 256; ++v) s += fabsf(C[(size_t)i * 65536 + (size_t)v * 256 + u]);
    red[u] = s;
    __syncthreads();
    for (int off = 128; off > 0; off >>= 1) {
        if (u < off) red[u] = fmaxf(red[u], red[u + off]);
        __syncthreads();
    }
    if (u == 0) alpha[i] = red[0];
}

// X0 = (2/(2+alpha)) * I
__launch_bounds__(256)
__global__ void init_X(float* __restrict__ X, const float* __restrict__ alpha)
{
    const int i = blockIdx.y;
    const float beta = 2.f / (2.f + alpha[i]);
    const int idx4 = (blockIdx.x * 256 + threadIdx.x) * 4;
    const int u = idx4 >> 8;
    const int v = idx4 & 255;
    float4 r;
    r.x = (v     == u) ? beta : 0.f;
    r.y = (v + 1 == u) ? beta : 0.f;
    r.z = (v + 2 == u) ? beta : 0.f;
    r.w = (v + 3 == u) ? beta : 0.f;
    *(float4*)&X[(size_t)i * 65536 + idx4] = r;
}

// out[b,o] = sum_u V0[u,b]*W_out[u,o] + b_out[o]
__launch_bounds__(256)
__global__ void out_kernel(const float* __restrict__ V0, const float* __restrict__ Wo,
                           const float* __restrict__ bo, float* __restrict__ out)
{
    __shared__ float Wl[2560];
    __shared__ float bl[16];
    const int t = threadIdx.x;
    for (int idx = t; idx < 2560; idx += 256) Wl[idx] = Wo[idx];
    if (t < OUT_DIM) bl[t] = bo[t];
    __syncthreads();
    const int b = blockIdx.x * 256 + t;
    float acc[OUT_DIM];
#pragma unroll
    for (int o = 0; o < OUT_DIM; ++o) acc[o] = bl[o];
    for (int u = 0; u < 256; ++u) {
        const float v = V0[(size_t)u * BATCH_N + b];
#pragma unroll
        for (int o = 0; o < OUT_DIM; ++o) acc[o] += v * Wl[u * OUT_DIM + o];
    }
#pragma unroll
    for (int o = 0; o < OUT_DIM; ++o) out[(size_t)b * OUT_DIM + o] = acc[o];
}

extern "C" void kernel_launch(void* const* d_in, const int* in_sizes, int n_in,
                              void* d_out, int out_size, void* d_ws, size_t ws_size,
                              hipStream_t stream)
{
    const float* x    = (const float*)d_in[0];
    const float* W_in = (const float*)d_in[1];
    const float* b_in = (const float*)d_in[2];
    const float* B0   = (const float*)d_in[3];
    const float* q    = (const float*)d_in[4];
    const float* W_out= (const float*)d_in[5];
    const float* b_out= (const float*)d_in[6];
    float* out = (float*)d_out;

    float* ws = (float*)d_ws;
    const size_t VN = (size_t)UNITS_N * BATCH_N;  // 8388608
    float* V0    = ws;
    float* V1    = V0 + VN;
    float* T     = V1 + VN;
    float* C     = T  + VN;            // 8*65536
    float* X     = C  + 8 * 65536;
    float* X2    = X  + 8 * 65536;
    float* Y     = X2 + 8 * 65536;
    float* Bt    = Y  + 8 * 65536;
    float* bq    = Bt + 8 * 65536;
    float* alpha = bq + 8 * 256;

    // ---- per-layer matrix prep ----
    transpose256<<<dim3(8, 8, 8), dim3(32, 8), 0, stream>>>(B0, Bt);
    bq_kernel<<<8, 256, 0, stream>>>(B0, q, bq);
    gemm256b<1><<<dim3(4, 4, 8), 256, 0, stream>>>(C, B0, B0, nullptr); // C = B^T B + 2I
    alpha_kernel<<<8, 256, 0, stream>>>(C, alpha);
    init_X<<<dim3(64, 8), 256, 0, stream>>>(X, alpha);
    float* Xc = X; float* Xn = X2;
    for (int it = 0; it < 7; ++it) {   // Newton-Schulz: X <- 2X - X C X
        gemm256b<0><<<dim3(4, 4, 8), 256, 0, stream>>>(Y, C, Xc, nullptr);
        gemm256b<2><<<dim3(4, 4, 8), 256, 0, stream>>>(Xn, Xc, Y, Xc);
        float* tmp = Xc; Xc = Xn; Xn = tmp;
    }
    // Xc now holds M_i = (B_i^T B_i + 2I)^{-1}

    // ---- input layer: V0 = (x @ W_in + b_in)^T, V1 = tanh(V0) ----
    gemm_input<<<dim3(BATCH_N / 128, 2), 256, 0, stream>>>(x, W_in, b_in, V0, V1);

    // ---- 8 implicit layers ----
    for (int i = 0; i < NLAYERS; ++i) {
        const float* Bi  = B0 + (size_t)i * 65536;
        const float* Bti = Bt + (size_t)i * 65536;
        const float* Mi  = Xc + (size_t)i * 65536;
        // T = V1 + tanh(V0) + B^T V0 + bq_i
        gemm_layer<1><<<dim3(BATCH_N / 128, 2), 256, 0, stream>>>(
            Bi, V0, T, V0, V1, bq + i * 256, 1.f);
        // V1 (=z1) = M @ T   (M symmetric => k-major access valid)
        gemm_layer<0><<<dim3(BATCH_N / 128, 2), 256, 0, stream>>>(
            Mi, T, V1, nullptr, nullptr, nullptr, 0.f);
        // V0 (=z0) = V0 + 0.1*q_i - B @ z1   (uses B^T copy for k-major access)
        gemm_layer<2><<<dim3(BATCH_N / 128, 2), 256, 0, stream>>>(
            Bti, V1, V0, V0, nullptr, q + i * 256, 0.1f);
    }

    // ---- output layer ----
    out_kernel<<<BATCH_N / 256, 256, 0, stream>>>(V0, W_out, b_out, out);
}

// Round 2
// 1650.021 us; speedup vs baseline: 1.1956x; 1.1956x over previous
//
#include <hip/hip_runtime.h>
#include <cstddef>
#include <cstdint>

#define BATCH_N 32768
#define OUT_DIM 10

typedef unsigned short u16;
typedef __attribute__((ext_vector_type(8))) short short8;
typedef __attribute__((ext_vector_type(4))) float f32x4;

__device__ __forceinline__ float bf2f(u16 h) {
    return __uint_as_float(((uint32_t)h) << 16);
}
__device__ __forceinline__ u16 f2bf(float v) {
    uint32_t b = __float_as_uint(v);
    b += 0x7FFFu + ((b >> 16) & 1u);
    return (u16)(b >> 16);
}
__device__ __forceinline__ void fsplit(float v, u16& h, u16& l) {
    h = f2bf(v);
    l = f2bf(v - bf2f(h));
}
__device__ __forceinline__ void gld16(const void* g, void* l) {
    __builtin_amdgcn_global_load_lds(
        (const __attribute__((address_space(1))) unsigned int*)g,
        (__attribute__((address_space(3))) unsigned int*)l, 16, 0, 0);
}

// ============================================================================
// MFMA GEMM: OutT[b][u] = EPI( sum_k InT[b][k] * W[k][u] ), K=256.
// In (A-op) = bf16 hi/lo [b][256]; Wpack (B-op) = bf16 hi/lo [u][256]
// (Wpack[u][k] = W[k][u]). bf16x3 split product, fp32 accumulate in MFMA.
// BM=BN=128, 4 waves of 64x64 (4x4 tiles of 16x16x32).
// EPI 0 (z1): out = acc
// EPI 1 (t):  out = acc + P2 + tanh(P1) + rowv[u]          (rowv = bq, pre-scaled)
// EPI 2 (z0): out = P1 + rowv[u]*rowscale - acc            (rowv = q, scale 0.1)
// ============================================================================
template<int EPI>
__global__ __launch_bounds__(256, 2)
void gemm_mfma(const u16* __restrict__ Ah, const u16* __restrict__ Al,
               const u16* __restrict__ Wh, const u16* __restrict__ Wl,
               u16* __restrict__ Oh, u16* __restrict__ Ol,
               const u16* __restrict__ P1h, const u16* __restrict__ P1l,
               const u16* __restrict__ P2h, const u16* __restrict__ P2l,
               const float* __restrict__ rowv, float rowscale)
{
    __shared__ u16 lds[16384];   // Ah[0..4095] Al[..8191] Wh[..12287] Wl[..16383]
    const int t = threadIdx.x;
    const int wave = t >> 6, lane = t & 63;
    const int b0 = blockIdx.x * 128, u0 = blockIdx.y * 128;

    // staging: wave w stages array w (8 chunks of 1KB each per K-step)
    const u16* gp = (wave == 0) ? Ah : (wave == 1) ? Al : (wave == 2) ? Wh : Wl;
    const int rowbase = (wave < 2) ? b0 : u0;
    u16* lb = &lds[wave * 4096];
    size_t goff[8];
#pragma unroll
    for (int j = 0; j < 8; ++j) {
        int r = rowbase + (j & 1) * 64 + lane;
        goff[j] = (size_t)r * 256 + (size_t)((j >> 1) * 8);
    }

    f32x4 acc[4][4];
#pragma unroll
    for (int a = 0; a < 4; ++a)
#pragma unroll
        for (int b = 0; b < 4; ++b) acc[a][b] = (f32x4){0.f, 0.f, 0.f, 0.f};

    const int wm = wave >> 1, wn = wave & 1;
    const int fl = lane & 15, kq = lane >> 4;

    for (int k0 = 0; k0 < 256; k0 += 32) {
        __syncthreads();
#pragma unroll
        for (int j = 0; j < 8; ++j)
            gld16(gp + goff[j] + k0, lb + j * 512);
        __syncthreads();
        short8 afh[4], aflo[4];
#pragma unroll
        for (int mt = 0; mt < 4; ++mt) {
            const int moff = kq * 1024 + (wm * 64 + mt * 16 + fl) * 8;
            afh[mt]  = *(const short8*)&lds[moff];
            aflo[mt] = *(const short8*)&lds[4096 + moff];
        }
#pragma unroll
        for (int nt = 0; nt < 4; ++nt) {
            const int noff = kq * 1024 + (wn * 64 + nt * 16 + fl) * 8;
            short8 bfh = *(const short8*)&lds[8192 + noff];
            short8 bfl = *(const short8*)&lds[12288 + noff];
#pragma unroll
            for (int mt = 0; mt < 4; ++mt) {
                acc[mt][nt] = __builtin_amdgcn_mfma_f32_16x16x32_bf16(afh[mt],  bfh, acc[mt][nt], 0, 0, 0);
                acc[mt][nt] = __builtin_amdgcn_mfma_f32_16x16x32_bf16(afh[mt],  bfl, acc[mt][nt], 0, 0, 0);
                acc[mt][nt] = __builtin_amdgcn_mfma_f32_16x16x32_bf16(aflo[mt], bfh, acc[mt][nt], 0, 0, 0);
            }
        }
    }

    // epilogue: C/D layout (16x16): col=lane&15 -> u ; row=(lane>>4)*4+reg -> b
#pragma unroll
    for (int mt = 0; mt < 4; ++mt) {
#pragma unroll
        for (int nt = 0; nt < 4; ++nt) {
            const int u = u0 + wn * 64 + nt * 16 + fl;
            const int brow = b0 + wm * 64 + mt * 16 + kq * 4;
#pragma unroll
            for (int r = 0; r < 4; ++r) {
                const size_t idx = (size_t)(brow + r) * 256 + u;
                float v = acc[mt][nt][r];
                if (EPI == 1) {
                    float p1 = bf2f(P1h[idx]) + bf2f(P1l[idx]);
                    float p2 = bf2f(P2h[idx]) + bf2f(P2l[idx]);
                    v = v + p2 + tanhf(p1) + rowv[u];
                } else if (EPI == 2) {
                    float p1 = bf2f(P1h[idx]) + bf2f(P1l[idx]);
                    v = p1 + rowv[u] * rowscale - v;
                }
                u16 h, l; fsplit(v, h, l);
                Oh[idx] = h; Ol[idx] = l;
            }
        }
    }
}

// ============================================================================
// Input MFMA GEMM: V0T[b][u] = x[b][:784] @ W_in + b_in ; V1 = tanh(V0).
// A (x) staged fp32->bf16 hi/lo in-kernel; W prepacked [256 u][800 k] (zero-pad).
// ============================================================================
__global__ __launch_bounds__(256, 2)
void gemm_mfma_input(const float* __restrict__ X,
                     const u16* __restrict__ Wh, const u16* __restrict__ Wl,
                     const float* __restrict__ bias,
                     u16* __restrict__ V0h, u16* __restrict__ V0l,
                     u16* __restrict__ V1h, u16* __restrict__ V1l)
{
    __shared__ u16 lds[16384];
    const int t = threadIdx.x;
    const int wave = t >> 6, lane = t & 63;
    const int b0 = blockIdx.x * 128, u0 = blockIdx.y * 128;

    // B staging: waves 0,1 -> Wh ; waves 2,3 -> Wl ; 4 chunks each
    const u16* gp = (wave < 2) ? Wh : Wl;
    u16* lbB = &lds[(wave < 2) ? 8192 : 12288];
    size_t goffB[4];
    int jB[4];
#pragma unroll
    for (int i = 0; i < 4; ++i) {
        int j = (wave & 1) * 4 + i;
        jB[i] = j;
        int r = u0 + (j & 1) * 64 + lane;
        goffB[i] = (size_t)r * 800 + (size_t)((j >> 1) * 8);
    }
    // A staging (fp32 convert): thread handles row m = t&127, k-half (t>>7)*16
    const int am = t & 127, akh = t >> 7;
    const size_t arow = (size_t)(b0 + am) * 784;

    f32x4 acc[4][4];
#pragma unroll
    for (int a = 0; a < 4; ++a)
#pragma unroll
        for (int b = 0; b < 4; ++b) acc[a][b] = (f32x4){0.f, 0.f, 0.f, 0.f};

    const int wm = wave >> 1, wn = wave & 1;
    const int fl = lane & 15, kq = lane >> 4;

    for (int k0 = 0; k0 < 800; k0 += 32) {
        __syncthreads();
#pragma unroll
        for (int i = 0; i < 4; ++i)
            gld16(gp + goffB[i] + k0, lbB + ((wave & 1) * 4 + i) * 512);
#pragma unroll
        for (int c = 0; c < 4; ++c) {
            const int gk = k0 + akh * 16 + c * 4;
            float4 v = *(const float4*)(X + arow + (gk < 784 ? gk : 0));
            u16 hs0, ls0, hs1, ls1, hs2, ls2, hs3, ls3;
            fsplit(v.x, hs0, ls0); fsplit(v.y, hs1, ls1);
            fsplit(v.z, hs2, ls2); fsplit(v.w, hs3, ls3);
            const int kl = akh * 16 + c * 4;
            const int off = (kl >> 3) * 1024 + am * 8 + (kl & 7);
            ushort4 hv; hv.x = hs0; hv.y = hs1; hv.z = hs2; hv.w = hs3;
            ushort4 lv; lv.x = ls0; lv.y = ls1; lv.z = ls2; lv.w = ls3;
            *(ushort4*)&lds[off] = hv;
            *(ushort4*)&lds[4096 + off] = lv;
        }
        __syncthreads();
        short8 afh[4], aflo[4];
#pragma unroll
        for (int mt = 0; mt < 4; ++mt) {
            const int moff = kq * 1024 + (wm * 64 + mt * 16 + fl) * 8;
            afh[mt]  = *(const short8*)&lds[moff];
            aflo[mt] = *(const short8*)&lds[4096 + moff];
        }
#pragma unroll
        for (int nt = 0; nt < 4; ++nt) {
            const int noff = kq * 1024 + (wn * 64 + nt * 16 + fl) * 8;
            short8 bfh = *(const short8*)&lds[8192 + noff];
            short8 bfl = *(const short8*)&lds[12288 + noff];
#pragma unroll
            for (int mt = 0; mt < 4; ++mt) {
                acc[mt][nt] = __builtin_amdgcn_mfma_f32_16x16x32_bf16(afh[mt],  bfh, acc[mt][nt], 0, 0, 0);
                acc[mt][nt] = __builtin_amdgcn_mfma_f32_16x16x32_bf16(afh[mt],  bfl, acc[mt][nt], 0, 0, 0);
                acc[mt][nt] = __builtin_amdgcn_mfma_f32_16x16x32_bf16(aflo[mt], bfh, acc[mt][nt], 0, 0, 0);
            }
        }
    }

#pragma unroll
    for (int mt = 0; mt < 4; ++mt) {
#pragma unroll
        for (int nt = 0; nt < 4; ++nt) {
            const int u = u0 + wn * 64 + nt * 16 + fl;
            const int brow = b0 + wm * 64 + mt * 16 + kq * 4;
            const float bu = bias[u];
#pragma unroll
            for (int r = 0; r < 4; ++r) {
                const size_t idx = (size_t)(brow + r) * 256 + u;
                float v0 = acc[mt][nt][r] + bu;
                float v1 = tanhf(v0);
                u16 h, l;
                fsplit(v0, h, l); V0h[idx] = h; V0l[idx] = l;
                fsplit(v1, h, l); V1h[idx] = h; V1l[idx] = l;
            }
        }
    }
}

// ============================================================================
// fp32 prep kernels (small 256x256 work, off the critical path)
// ============================================================================
template<int EPI>
__launch_bounds__(256)
__global__ void gemm256b(float* __restrict__ D, const float* __restrict__ A,
                         const float* __restrict__ Bm, const float* __restrict__ E)
{
    __shared__ float As[16][64];
    __shared__ float Bs[16][64];
    const int i = blockIdx.z;
    const size_t off = (size_t)i * 65536;
    const float* Ai = A + off;
    const float* Bi = Bm + off;
    const int t  = threadIdx.x;
    const int tx = t & 15, ty = t >> 4;
    const int u0 = blockIdx.y * 64, v0 = blockIdx.x * 64;
    const int lk = t >> 4, lv = (t & 15) << 2;

    float acc[4][4];
#pragma unroll
    for (int m = 0; m < 4; ++m)
#pragma unroll
        for (int n = 0; n < 4; ++n) acc[m][n] = 0.f;

    for (int k0 = 0; k0 < 256; k0 += 16) {
        __syncthreads();
        *(float4*)&As[lk][lv] = *(const float4*)(Ai + (size_t)(k0 + lk) * 256 + u0 + lv);
        *(float4*)&Bs[lk][lv] = *(const float4*)(Bi + (size_t)(k0 + lk) * 256 + v0 + lv);
        __syncthreads();
#pragma unroll
        for (int kk = 0; kk < 16; ++kk) {
            float af[4], bf[4];
            *(float4*)&af[0] = *(const float4*)&As[kk][ty * 4];
            *(float4*)&bf[0] = *(const float4*)&Bs[kk][tx * 4];
#pragma unroll
            for (int m = 0; m < 4; ++m)
#pragma unroll
                for (int n = 0; n < 4; ++n) acc[m][n] += af[m] * bf[n];
        }
    }

#pragma unroll
    for (int m = 0; m < 4; ++m) {
        const int u = u0 + ty * 4 + m;
        const size_t idx = off + (size_t)u * 256 + v0 + tx * 4;
        float4 r; float* rf = &r.x;
        if (EPI == 0) {
#pragma unroll
            for (int n = 0; n < 4; ++n) rf[n] = acc[m][n];
        } else if (EPI == 1) {
#pragma unroll
            for (int n = 0; n < 4; ++n)
                rf[n] = acc[m][n] + ((u == v0 + tx * 4 + n) ? 2.f : 0.f);
        } else {
            float4 e = *(const float4*)&E[idx];
            const float* ef = &e.x;
#pragma unroll
            for (int n = 0; n < 4; ++n) rf[n] = 2.f * ef[n] - acc[m][n];
        }
        *(float4*)&D[idx] = r;
    }
}

__launch_bounds__(256)
__global__ void transpose256(const float* __restrict__ src, float* __restrict__ dst)
{
    __shared__ float tl[32][33];
    const int i = blockIdx.z;
    const float* S = src + (size_t)i * 65536;
    float* Dst = dst + (size_t)i * 65536;
    const int u0 = blockIdx.y * 32, k0 = blockIdx.x * 32;
    const int tx = threadIdx.x, ty = threadIdx.y; // 32 x 8
#pragma unroll
    for (int r = 0; r < 32; r += 8) tl[ty + r][tx] = S[(size_t)(u0 + ty + r) * 256 + k0 + tx];
    __syncthreads();
#pragma unroll
    for (int r = 0; r < 32; r += 8) Dst[(size_t)(k0 + ty + r) * 256 + u0 + tx] = tl[tx][ty + r];
}

__launch_bounds__(256)
__global__ void bq_kernel(const float* __restrict__ B0, const float* __restrict__ q,
                          float* __restrict__ bq)
{
    __shared__ float qs[256];
    const int i = blockIdx.x;
    const int u = threadIdx.x;
    qs[u] = q[i * 256 + u];
    __syncthreads();
    float s = 0.f;
    for (int k = 0; k < 256; ++k) s += B0[(size_t)i * 65536 + (size_t)k * 256 + u] * qs[k];
    bq[i * 256 + u] = 0.1f * s;
}

__launch_bounds__(256)
__global__ void alpha_kernel(const float* __restrict__ C, float* __restrict__ alpha)
{
    __shared__ float red[256];
    const int i = blockIdx.x;
    const int u = threadIdx.x;
    float s = 0.f;
    for (int v = 0; v < 256; ++v) s += fabsf(C[(size_t)i * 65536 + (size_t)v * 256 + u]);
    red[u] = s;
    __syncthreads();
    for (int off = 128; off > 0; off >>= 1) {
        if (u < off) red[u] = fmaxf(red[u], red[u + off]);
        __syncthreads();
    }
    if (u == 0) alpha[i] = red[0];
}

__launch_bounds__(256)
__global__ void init_X(float* __restrict__ X, const float* __restrict__ alpha)
{
    const int i = blockIdx.y;
    const float beta = 2.f / (2.f + alpha[i]);
    const int idx4 = (blockIdx.x * 256 + threadIdx.x) * 4;
    const int u = idx4 >> 8;
    const int v = idx4 & 255;
    float4 r;
    r.x = (v     == u) ? beta : 0.f;
    r.y = (v + 1 == u) ? beta : 0.f;
    r.z = (v + 2 == u) ? beta : 0.f;
    r.w = (v + 3 == u) ? beta : 0.f;
    *(float4*)&X[(size_t)i * 65536 + idx4] = r;
}

// fp32 -> bf16 hi/lo direct pack (same layout)
__launch_bounds__(256)
__global__ void pack_split(const float* __restrict__ src, u16* __restrict__ h,
                           u16* __restrict__ l, int n4)
{
    int i = blockIdx.x * 256 + threadIdx.x;
    if (i >= n4) return;
    float4 v = ((const float4*)src)[i];
    u16 h0, l0, h1, l1, h2, l2, h3, l3;
    fsplit(v.x, h0, l0); fsplit(v.y, h1, l1);
    fsplit(v.z, h2, l2); fsplit(v.w, h3, l3);
    ushort4 hv; hv.x = h0; hv.y = h1; hv.z = h2; hv.w = h3;
    ushort4 lv; lv.x = l0; lv.y = l1; lv.z = l2; lv.w = l3;
    *(ushort4*)&h[(size_t)i * 4] = hv;
    *(ushort4*)&l[(size_t)i * 4] = lv;
}

// W_in [784][256] -> Wpack [256 u][800 k] (transposed, zero-padded), bf16 hi/lo
__global__ void pack_win(const float* __restrict__ Wi, u16* __restrict__ h, u16* __restrict__ l)
{
    int k = blockIdx.x * 256 + threadIdx.x;
    int u = blockIdx.y;
    if (k >= 800) return;
    float v = (k < 784) ? Wi[(size_t)k * 256 + u] : 0.f;
    u16 hh, ll; fsplit(v, hh, ll);
    h[(size_t)u * 800 + k] = hh;
    l[(size_t)u * 800 + k] = ll;
}

// out[b,o] = sum_u v0T[b][u] * W_out[u][o] + b_out[o]
__launch_bounds__(256)
__global__ void out_kernel(const u16* __restrict__ V0h, const u16* __restrict__ V0l,
                           const float* __restrict__ Wo, const float* __restrict__ bo,
                           float* __restrict__ out)
{
    __shared__ float Wl_s[2560];
    const int t = threadIdx.x;
    for (int i = t; i < 2560; i += 256) Wl_s[i] = Wo[i];
    __syncthreads();
    const int b = blockIdx.x * 256 + t;
    float acc[OUT_DIM];
#pragma unroll
    for (int o = 0; o < OUT_DIM; ++o) acc[o] = bo[o];
    const size_t base = (size_t)b * 256;
    for (int u8 = 0; u8 < 256; u8 += 8) {
        uint4 hv = *(const uint4*)&V0h[base + u8];
        uint4 lv = *(const uint4*)&V0l[base + u8];
        const uint32_t* hw = &hv.x; const uint32_t* lw = &lv.x;
#pragma unroll
        for (int p = 0; p < 4; ++p) {
            float e0 = __uint_as_float(hw[p] << 16) + __uint_as_float(lw[p] << 16);
            float e1 = __uint_as_float(hw[p] & 0xFFFF0000u) + __uint_as_float(lw[p] & 0xFFFF0000u);
            const float* w0 = &Wl_s[(u8 + p * 2) * OUT_DIM];
#pragma unroll
            for (int o = 0; o < OUT_DIM; ++o) acc[o] += e0 * w0[o] + e1 * w0[OUT_DIM + o];
        }
    }
#pragma unroll
    for (int o = 0; o < OUT_DIM; ++o) out[(size_t)b * OUT_DIM + o] = acc[o];
}

extern "C" void kernel_launch(void* const* d_in, const int* in_sizes, int n_in,
                              void* d_out, int out_size, void* d_ws, size_t ws_size,
                              hipStream_t stream)
{
    const float* x     = (const float*)d_in[0];
    const float* W_in  = (const float*)d_in[1];
    const float* b_in  = (const float*)d_in[2];
    const float* B0    = (const float*)d_in[3];
    const float* q     = (const float*)d_in[4];
    const float* W_out = (const float*)d_in[5];
    const float* b_out = (const float*)d_in[6];

    const size_t VN = (size_t)256 * BATCH_N;   // 8388608 elements
    u16* U   = (u16*)d_ws;
    u16* V0h = U;            u16* V0l = U + VN;
    u16* V1h = U + 2 * VN;   u16* V1l = U + 3 * VN;
    u16* Th  = U + 4 * VN;   u16* Tl  = U + 5 * VN;
    u16* Wth = U + 6 * VN;
    u16* Wtl = Wth + 524288;
    u16* Wmh = Wtl + 524288; u16* Wml = Wmh + 524288;
    u16* Wbh = Wml + 524288; u16* Wbl = Wbh + 524288;
    u16* Wih = Wbl + 524288; u16* Wil = Wih + 204800;
    float* bq    = (float*)(Wil + 204800);
    float* alpha = bq + 2048;

    // fp32 prep scratch aliased into activation slots (all prep finishes before
    // the input GEMM first writes activations; stream-ordered => safe)
    float* Bt = (float*)V0h;
    float* C  = (float*)V0l;
    float* X  = (float*)V1h;
    float* X2 = (float*)V1l;
    float* Y  = (float*)Th;

    // ---- per-layer matrix prep (fp32) ----
    transpose256<<<dim3(8, 8, 8), dim3(32, 8), 0, stream>>>(B0, Bt);
    bq_kernel<<<8, 256, 0, stream>>>(B0, q, bq);
    gemm256b<1><<<dim3(4, 4, 8), 256, 0, stream>>>(C, B0, B0, nullptr); // C = B^T B + 2I
    alpha_kernel<<<8, 256, 0, stream>>>(C, alpha);
    init_X<<<dim3(64, 8), 256, 0, stream>>>(X, alpha);
    float* Xc = X; float* Xn = X2;
    for (int it = 0; it < 6; ++it) {   // Newton-Schulz: X <- 2X - X C X
        gemm256b<0><<<dim3(4, 4, 8), 256, 0, stream>>>(Y, C, Xc, nullptr);
        gemm256b<2><<<dim3(4, 4, 8), 256, 0, stream>>>(Xn, Xc, Y, Xc);
        float* tmp = Xc; Xc = Xn; Xn = tmp;
    }
    // Xc = M_i = (B_i^T B_i + 2I)^{-1}

    // ---- bf16 hi/lo weight packs ----
    pack_split<<<512, 256, 0, stream>>>(Bt, Wth, Wtl, 131072);  // Wpack_t  = B0^T
    pack_split<<<512, 256, 0, stream>>>(Xc, Wmh, Wml, 131072);  // Wpack_z1 = M
    pack_split<<<512, 256, 0, stream>>>(B0, Wbh, Wbl, 131072);  // Wpack_z0 = B0
    pack_win<<<dim3(4, 256), 256, 0, stream>>>(W_in, Wih, Wil);

    // ---- input layer ----
    gemm_mfma_input<<<dim3(256, 2), 256, 0, stream>>>(x, Wih, Wil, b_in,
                                                      V0h, V0l, V1h, V1l);

    // ---- 8 implicit layers ----
    for (int i = 0; i < 8; ++i) {
        const size_t wo = (size_t)i * 65536;
        // T = v1 + tanh(v0) + B^T v0 + 0.1 B^T q
        gemm_mfma<1><<<dim3(256, 2), 256, 0, stream>>>(
            V0h, V0l, Wth + wo, Wtl + wo, Th, Tl,
            V0h, V0l, V1h, V1l, bq + i * 256, 1.f);
        // z1 = M T
        gemm_mfma<0><<<dim3(256, 2), 256, 0, stream>>>(
            Th, Tl, Wmh + wo, Wml + wo, V1h, V1l,
            nullptr, nullptr, nullptr, nullptr, nullptr, 0.f);
        // z0 = v0 + 0.1 q - B z1
        gemm_mfma<2><<<dim3(256, 2), 256, 0, stream>>>(
            V1h, V1l, Wbh + wo, Wbl + wo, V0h, V0l,
            V0h, V0l, nullptr, nullptr, q + i * 256, 0.1f);
    }

    // ---- output layer ----
    out_kernel<<<BATCH_N / 256, 256, 0, stream>>>(V0h, V0l, W_out, b_out, (float*)d_out);
}